// Round 6
// baseline (558.945 us; speedup 1.0000x reference)
//
#include <hip/hip_runtime.h>
#include <cstddef>

#define HW 4096
#define PL 4752            // padded plane: 66 rows x 72 cols
#define RS 72
#define APL (2048 * 4752)  // per-array stride (2048 planes)

typedef short bf16x8 __attribute__((ext_vector_type(8)));
typedef unsigned short u16x8 __attribute__((ext_vector_type(8)));
typedef float f32x4 __attribute__((ext_vector_type(4)));
typedef unsigned int u32x4 __attribute__((ext_vector_type(4)));
typedef unsigned int u32x2 __attribute__((ext_vector_type(2)));

__device__ __forceinline__ unsigned short f2bf(float f) {
    unsigned u = __builtin_bit_cast(unsigned, f);
    u += 0x7fffu + ((u >> 16) & 1u);
    return (unsigned short)(u >> 16);
}
__device__ __forceinline__ float bf2f(unsigned short s) {
    return __builtin_bit_cast(float, ((unsigned)s) << 16);
}

// ---------------- prep: fp32 -> bf16 weights ----------------
__global__ __launch_bounds__(256) void kprep(
    const float* __restrict__ w1, const float* __restrict__ w2, const float* __restrict__ w5,
    const float* __restrict__ b1, const float* __restrict__ b2,
    unsigned short* __restrict__ wcat, unsigned short* __restrict__ wb5,
    float* __restrict__ bcat)
{
    const int i = blockIdx.x * 256 + threadIdx.x;
    if (i < 384 * 64) {
        const int r = i >> 6;
        wcat[i] = f2bf(r < 192 ? w2[i] : w1[i - 192 * 64]);
    }
    if (i < 128 * 128) wb5[i] = f2bf(w5[i]);
    if (i < 384) bcat[i] = (i < 192) ? b2[i] : b1[i - 192];
}

// ---------------- zero the halo borders of all lqkv planes ----------------
__global__ __launch_bounds__(256) void kzero(unsigned short* __restrict__ lqkv)
{
    unsigned short* plane = lqkv + (size_t)blockIdx.x * PL;
    for (int i = threadIdx.x; i < 656; i += 256) {
        int idx;
        if (i < 144) {
            const int r = (i < 72) ? 0 : 65;
            idx = r * RS + (i % 72);
        } else {
            const int j = i - 144;
            const int r = 1 + (j >> 3);
            const int cs = j & 7;
            idx = r * RS + (cs < 4 ? cs : 64 + cs);
        }
        plane[idx] = 0;
    }
}

// ---------------- K1: LayerNorm + fc1/fc2 via MFMA + pooled K/V ----------------
__global__ __launch_bounds__(256) void k1_ln_fc(
    const float* __restrict__ x, const float* __restrict__ ng, const float* __restrict__ nb,
    const unsigned short* __restrict__ wcat, const float* __restrict__ bcat,
    float* __restrict__ gq, float* __restrict__ gkp, float* __restrict__ gvp,
    unsigned short* __restrict__ lqkv)
{
    __shared__ unsigned short xnT[64 * 128];   // [pixel][c] bf16, XOR-swizzled
    __shared__ float red[2][4][64];
    const int t = threadIdx.x;
    const int g = t >> 6;
    const int p = t & 63;
    const int bx = blockIdx.x;
    const int b = bx >> 6;
    const int h = bx & 63;
    const float* xrow = x + (size_t)b * 128 * HW + h * 64;

    float v[32];
    float s1 = 0.f, s2 = 0.f;
    #pragma unroll
    for (int i = 0; i < 32; ++i) {
        const int c = g * 32 + i;
        const float vv = xrow[(size_t)c * HW + p];
        v[i] = vv; s1 += vv; s2 += vv * vv;
    }
    red[0][g][p] = s1; red[1][g][p] = s2;
    __syncthreads();
    const float m   = (red[0][0][p] + red[0][1][p] + red[0][2][p] + red[0][3][p]) * (1.f / 128.f);
    const float var = (red[1][0][p] + red[1][1][p] + red[1][2][p] + red[1][3][p]) * (1.f / 128.f) - m * m;
    const float rstd = rsqrtf(var + 1e-5f);

    #pragma unroll
    for (int j = 0; j < 4; ++j) {
        u32x4 pk;
        #pragma unroll
        for (int q = 0; q < 4; ++q) {
            const int i0 = j * 8 + q * 2;
            const int c0 = g * 32 + i0;
            const float f0 = (v[i0]     - m) * rstd * ng[c0]     + nb[c0];
            const float f1 = (v[i0 + 1] - m) * rstd * ng[c0 + 1] + nb[c0 + 1];
            pk[q] = (unsigned)f2bf(f0) | ((unsigned)f2bf(f1) << 16);
        }
        const int colu = (g * 32 + j * 8) ^ ((p & 7) * 8);
        *reinterpret_cast<u32x4*>(&xnT[p * 128 + colu]) = pk;
    }
    __syncthreads();

    const int wid = g;
    const int lg = p >> 4, lr = p & 15;
    const int kbase = (wid >= 2) ? 64 : 0;

    bf16x8 afr[4][2];
    #pragma unroll
    for (int mt = 0; mt < 4; ++mt)
        #pragma unroll
        for (int kc = 0; kc < 2; ++kc) {
            const int pix = mt * 16 + lr;
            const int colu = (kbase + kc * 32 + lg * 8) ^ ((pix & 7) * 8);
            afr[mt][kc] = *reinterpret_cast<const bf16x8*>(&xnT[pix * 128 + colu]);
        }

    const int nbase = wid * 96;
    #pragma unroll
    for (int nt = 0; nt < 6; ++nt) {
        const int o0 = nbase + nt * 16;
        const int o  = o0 + lr;
        const float bias = bcat[o];
        f32x4 acc[4];
        #pragma unroll
        for (int mt = 0; mt < 4; ++mt) acc[mt] = f32x4{bias, bias, bias, bias};
        #pragma unroll
        for (int kc = 0; kc < 2; ++kc) {
            const bf16x8 bfr = *reinterpret_cast<const bf16x8*>(&wcat[(size_t)o * 64 + kc * 32 + lg * 8]);
            #pragma unroll
            for (int mt = 0; mt < 4; ++mt)
                acc[mt] = __builtin_amdgcn_mfma_f32_16x16x32_bf16(afr[mt][kc], bfr, acc[mt], 0, 0, 0);
        }
        if (o0 < 192) {
            // fc2 -> lqkv bf16 padded: [arr][(b*4+lh)*16+cl][(h+1)*72 + 4 + w]
            const int cc = o0 >> 6;
            const int lh2 = (o0 & 63) >> 4;
            unsigned short* dst = lqkv + (size_t)cc * APL
                                + (((size_t)b * 4 + lh2) * 16 + lr) * PL
                                + (size_t)(h + 1) * RS + 4;
            #pragma unroll
            for (int mt = 0; mt < 4; ++mt) {
                u32x2 pk;
                pk[0] = (unsigned)f2bf(acc[mt][0]) | ((unsigned)f2bf(acc[mt][1]) << 16);
                pk[1] = (unsigned)f2bf(acc[mt][2]) | ((unsigned)f2bf(acc[mt][3]) << 16);
                *reinterpret_cast<u32x2*>(&dst[mt * 16 + lg * 4]) = pk;
            }
        } else if (o0 < 256) {
            // fc1 q -> gq [b][gh][cg][n] f32
            const int gh = (o0 - 192) >> 4;
            float* dst = gq + (((size_t)b * 4 + gh) * 16) * HW;
            #pragma unroll
            for (int mt = 0; mt < 4; ++mt)
                *reinterpret_cast<f32x4*>(&dst[(size_t)lr * HW + h * 64 + mt * 16 + lg * 4]) = acc[mt];
        } else {
            // fc1 k,v -> pooled [b][gh][m][cg]
            const int kvsel = (o0 - 256) >> 6;
            const int gh = ((o0 - 256) & 63) >> 4;
            float* dst = (kvsel ? gvp : gkp) + (((size_t)b * 4 + gh) * 64 + (h >> 3) * 8) * 16;
            #pragma unroll
            for (int mt = 0; mt < 4; ++mt) {
                float s = acc[mt][0] + acc[mt][1] + acc[mt][2] + acc[mt][3];
                s += __shfl_xor(s, 16);
                if (!(p & 16))
                    atomicAdd(&dst[(2 * mt + (lg >> 1)) * 16 + lr], s * (1.f / 64.f));
            }
        }
    }
}

// ---------------- K2: global attention (64 pooled tokens), K/V in LDS ----------------
__global__ __launch_bounds__(256) void k2_attn(
    const float* __restrict__ gq, const float* __restrict__ gkp,
    const float* __restrict__ gvp, float* __restrict__ out)
{
    __shared__ float skv[2][64][16];
    const int t = threadIdx.x;
    const int bx = blockIdx.x;
    const int tile = bx & 15;
    const int bg = bx >> 4;
    const int b = bg >> 2;
    const int gh = bg & 3;
    for (int i = t; i < 1024; i += 256) {
        skv[0][i >> 4][i & 15] = gkp[(size_t)bg * 1024 + i];
        skv[1][i >> 4][i & 15] = gvp[(size_t)bg * 1024 + i];
    }
    __syncthreads();
    const int n = tile * 256 + t;
    const float* qp = gq + (size_t)bg * 16 * HW + n;
    float q[16];
    #pragma unroll
    for (int cg = 0; cg < 16; ++cg) q[cg] = qp[(size_t)cg * HW] * 0.125f;
    float s[64];
    #pragma unroll
    for (int mm = 0; mm < 64; ++mm) {
        float a = 0.f;
        #pragma unroll
        for (int cg = 0; cg < 16; ++cg) a = fmaf(q[cg], skv[0][mm][cg], a);
        s[mm] = a;
    }
    float mx = s[0];
    #pragma unroll
    for (int mm = 1; mm < 64; ++mm) mx = fmaxf(mx, s[mm]);
    float sum = 0.f;
    #pragma unroll
    for (int mm = 0; mm < 64; ++mm) { float e = __expf(s[mm] - mx); s[mm] = e; sum += e; }
    const float rs = 1.f / sum;
    float acc[16];
    #pragma unroll
    for (int cg = 0; cg < 16; ++cg) acc[cg] = 0.f;
    #pragma unroll
    for (int mm = 0; mm < 64; ++mm) {
        const float pm = s[mm];
        #pragma unroll
        for (int cg = 0; cg < 16; ++cg) acc[cg] = fmaf(pm, skv[1][mm][cg], acc[cg]);
    }
    float* op = out + ((size_t)b * 128 + 64 + gh * 16) * HW + n;
    #pragma unroll
    for (int cg = 0; cg < 16; ++cg) op[(size_t)cg * HW] = acc[cg] * rs;
}

// ---------------- K3: local branch, padded bf16 input, pipelined staging ----------------
__global__ __launch_bounds__(256, 4) void k3_local(
    const unsigned short* __restrict__ lqkv,
    const float* __restrict__ qw, const float* __restrict__ qb,
    const float* __restrict__ kw, const float* __restrict__ kb,
    const float* __restrict__ vw, const float* __restrict__ vb,
    const float* __restrict__ w3, const float* __restrict__ b3,
    const float* __restrict__ w4, const float* __restrict__ b4,
    float* __restrict__ out)
{
    __shared__ float sb[3][4][6][RS];   // 20736 B, one 4-channel chunk
    const int t = threadIdx.x;
    const int w = t & 63;
    const int rr = t >> 6;
    const int bx = blockIdx.x;
    const int htile = bx & 15;
    const int bl = bx >> 4;             // b*4+lh
    const int b = bl >> 2;
    const int lh = bl & 3;
    const int h0 = htile * 4;
    const int h = h0 + rr;

    // ---- decode 3 staging tasks/thread: 648 = 3arr x 4ch x 6row x 9(chunks of 8) ----
    bool ton[3];
    size_t tgoff[3];
    int tloff[3];
    #pragma unroll
    for (int k = 0; k < 3; ++k) {
        const int s = t + 256 * k;
        ton[k] = (s < 648);
        const int arr = s / 216;
        const int r1 = s - arr * 216;
        const int ch = r1 / 54;
        const int r2 = r1 - ch * 54;
        const int row = r2 / 9;
        const int ck = r2 - row * 9;
        tgoff[k] = (size_t)arr * APL + ((size_t)bl * 16 + ch) * PL
                 + (size_t)(h0 + row) * RS + ck * 8;
        tloff[k] = ((arr * 4 + ch) * 6 + row) * RS + ck * 8;
    }
    float* sbf = &sb[0][0][0][0];

    float a[16], lvv[16];

    // prologue: stage chunk 0
    {
        u16x8 rg[3];
        #pragma unroll
        for (int k = 0; k < 3; ++k)
            if (ton[k]) rg[k] = *reinterpret_cast<const u16x8*>(lqkv + tgoff[k]);
        #pragma unroll
        for (int k = 0; k < 3; ++k)
            if (ton[k]) {
                f32x4 lo, hi;
                #pragma unroll
                for (int j = 0; j < 4; ++j) { lo[j] = bf2f(rg[k][j]); hi[j] = bf2f(rg[k][j + 4]); }
                *reinterpret_cast<f32x4*>(&sbf[tloff[k]])     = lo;
                *reinterpret_cast<f32x4*>(&sbf[tloff[k] + 4]) = hi;
            }
    }
    __syncthreads();

    #pragma unroll
    for (int c = 0; c < 4; ++c) {
        u16x8 rg[3];
        if (c < 3) {
            #pragma unroll
            for (int k = 0; k < 3; ++k)
                if (ton[k]) rg[k] = *reinterpret_cast<const u16x8*>(lqkv + tgoff[k] + (size_t)((c + 1) * 4) * PL);
        }
        // ---- compute chunk c from LDS (loads for c+1 in flight) ----
        #pragma unroll
        for (int ch = 0; ch < 4; ++ch) {
            const int cl = c * 4 + ch;
            float aq = qb[cl], ak = kb[cl], av = vb[cl];
            #pragma unroll
            for (int dy = 0; dy < 3; ++dy) {
                #pragma unroll
                for (int dx = 0; dx < 3; ++dx) {
                    const int wi = cl * 9 + dy * 3 + dx;
                    const int col = w + 3 + dx;
                    aq = fmaf(qw[wi], sb[0][ch][rr + dy][col], aq);
                    ak = fmaf(kw[wi], sb[1][ch][rr + dy][col], ak);
                    av = fmaf(vw[wi], sb[2][ch][rr + dy][col], av);
                }
            }
            a[cl] = aq * ak;
            lvv[cl] = av;
        }
        __syncthreads();            // everyone done reading chunk c
        if (c < 3) {
            #pragma unroll
            for (int k = 0; k < 3; ++k)
                if (ton[k]) {
                    f32x4 lo, hi;
                    #pragma unroll
                    for (int j = 0; j < 4; ++j) { lo[j] = bf2f(rg[k][j]); hi[j] = bf2f(rg[k][j + 4]); }
                    *reinterpret_cast<f32x4*>(&sbf[tloff[k]])     = lo;
                    *reinterpret_cast<f32x4*>(&sbf[tloff[k] + 4]) = hi;
                }
            __syncthreads();
        }
    }

    float a2[16];
    #pragma unroll
    for (int o = 0; o < 16; ++o) {
        float acc = b3[o];
        #pragma unroll
        for (int c2 = 0; c2 < 16; ++c2) acc = fmaf(w3[o * 16 + c2], a[c2], acc);
        a2[o] = acc / (1.f + __expf(-acc));
    }
    float* op = out + ((size_t)b * 128 + lh * 16) * HW + (size_t)h * 64 + w;
    #pragma unroll
    for (int o = 0; o < 16; ++o) {
        float acc = b4[o];
        #pragma unroll
        for (int c2 = 0; c2 < 16; ++c2) acc = fmaf(w4[o * 16 + c2], a2[c2], acc);
        const float z = acc * 8.f;
        const float e2 = __expf(-2.f * fabsf(z));
        float th = (1.f - e2) / (1.f + e2);
        th = copysignf(th, z);
        op[(size_t)o * HW] = th * lvv[o];
    }
}

// ---------------- K4: fc5 (128x128) via MFMA + residual, in-place ----------------
__global__ __launch_bounds__(256) void k4_fc5(
    const float* __restrict__ x, const unsigned short* __restrict__ wb5,
    const float* __restrict__ b5, float* __restrict__ out)
{
    __shared__ unsigned short xcT[64 * 128];
    const int t = threadIdx.x;
    const int g = t >> 6, p = t & 63;
    const int bx = blockIdx.x;
    const int b = bx >> 6, h = bx & 63;
    float* obase = out + (size_t)b * 128 * HW + h * 64;

    float v[32];
    #pragma unroll
    for (int i = 0; i < 32; ++i) v[i] = obase[(size_t)(g * 32 + i) * HW + p];
    #pragma unroll
    for (int j = 0; j < 4; ++j) {
        u32x4 pk;
        #pragma unroll
        for (int q = 0; q < 4; ++q) {
            const int i0 = j * 8 + q * 2;
            pk[q] = (unsigned)f2bf(v[i0]) | ((unsigned)f2bf(v[i0 + 1]) << 16);
        }
        const int colu = (g * 32 + j * 8) ^ ((p & 7) * 8);
        *reinterpret_cast<u32x4*>(&xcT[p * 128 + colu]) = pk;
    }
    __syncthreads();

    const int wid = g, lg = p >> 4, lr = p & 15;
    bf16x8 afr[4][4];
    #pragma unroll
    for (int mt = 0; mt < 4; ++mt)
        #pragma unroll
        for (int kc = 0; kc < 4; ++kc) {
            const int pix = mt * 16 + lr;
            const int colu = (kc * 32 + lg * 8) ^ ((pix & 7) * 8);
            afr[mt][kc] = *reinterpret_cast<const bf16x8*>(&xcT[pix * 128 + colu]);
        }
    const float* xrow = x + (size_t)b * 128 * HW + h * 64;
    #pragma unroll
    for (int nt = 0; nt < 2; ++nt) {
        const int o = wid * 32 + nt * 16 + lr;
        const float bias = b5[o];
        f32x4 acc[4];
        #pragma unroll
        for (int mt = 0; mt < 4; ++mt) acc[mt] = f32x4{bias, bias, bias, bias};
        #pragma unroll
        for (int kc = 0; kc < 4; ++kc) {
            const bf16x8 bfr = *reinterpret_cast<const bf16x8*>(&wb5[(size_t)o * 128 + kc * 32 + lg * 8]);
            #pragma unroll
            for (int mt = 0; mt < 4; ++mt)
                acc[mt] = __builtin_amdgcn_mfma_f32_16x16x32_bf16(afr[mt][kc], bfr, acc[mt], 0, 0, 0);
        }
        #pragma unroll
        for (int mt = 0; mt < 4; ++mt) {
            const size_t off = (size_t)o * HW + mt * 16 + lg * 4;
            const f32x4 xr = *reinterpret_cast<const f32x4*>(&xrow[off]);
            const f32x4 r = acc[mt] + xr;
            *reinterpret_cast<f32x4*>(&obase[off]) = r;
        }
    }
}

extern "C" void kernel_launch(void* const* d_in, const int* in_sizes, int n_in,
                              void* d_out, int out_size, void* d_ws, size_t ws_size,
                              hipStream_t stream) {
    const float* x  = (const float*)d_in[0];
    const float* ng = (const float*)d_in[1];
    const float* nb = (const float*)d_in[2];
    const float* w1 = (const float*)d_in[3];
    const float* b1 = (const float*)d_in[4];
    const float* w2 = (const float*)d_in[5];
    const float* b2 = (const float*)d_in[6];
    const float* qw = (const float*)d_in[7];
    const float* qb = (const float*)d_in[8];
    const float* kw = (const float*)d_in[9];
    const float* kb = (const float*)d_in[10];
    const float* vw = (const float*)d_in[11];
    const float* vb = (const float*)d_in[12];
    const float* w3 = (const float*)d_in[13];
    const float* b3 = (const float*)d_in[14];
    const float* w4 = (const float*)d_in[15];
    const float* b4 = (const float*)d_in[16];
    const float* w5 = (const float*)d_in[17];
    const float* b5 = (const float*)d_in[18];
    float* out = (float*)d_out;
    float* ws  = (float*)d_ws;

    float* gq  = ws;                                   // 8388608 f32  [b][gh][cg][n]
    float* gkp = gq  + 8388608;                        // 131072 f32   [b][gh][m][cg]
    float* gvp = gkp + 131072;                         // 131072 f32
    unsigned short* lqkv = (unsigned short*)(gvp + 131072);  // 3*2048*4752 bf16 padded
    unsigned short* wcat = lqkv + 3 * APL;             // 384*64 bf16 (rows 0..191=w2, 192..383=w1)
    unsigned short* wb5  = wcat + 384 * 64;            // 128*128 bf16
    float* bcat = (float*)(wb5 + 128 * 128);           // 384 f32 (b2|b1)

    kprep<<<96, 256, 0, stream>>>(w1, w2, w5, b1, b2, wcat, wb5, bcat);
    kzero<<<6144, 256, 0, stream>>>(lqkv);
    hipMemsetAsync(gkp, 0, 2 * 131072 * sizeof(float), stream);
    k1_ln_fc<<<2048, 256, 0, stream>>>(x, ng, nb, wcat, bcat, gq, gkp, gvp, lqkv);
    k2_attn<<<2048, 256, 0, stream>>>(gq, gkp, gvp, out);
    k3_local<<<2048, 256, 0, stream>>>(lqkv, qw, qb, kw, kb, vw, vb,
                                       w3, b3, w4, b4, out);
    k4_fc5<<<2048, 256, 0, stream>>>(x, wb5, b5, out);
}

// Round 7
// 411.520 us; speedup vs baseline: 1.3582x; 1.3582x over previous
//
#include <hip/hip_runtime.h>
#include <cstddef>

#define HW 4096
#define PL 4752            // padded plane: 66 rows x 72 cols (global)
#define RS 72
#define LRS 76             // LDS row stride (floats), decorrelates banks
#define APL (2048 * 4752)  // per-array stride (2048 planes)

typedef short bf16x8 __attribute__((ext_vector_type(8)));
typedef unsigned short u16x8 __attribute__((ext_vector_type(8)));
typedef float f32x4 __attribute__((ext_vector_type(4)));
typedef unsigned int u32x4 __attribute__((ext_vector_type(4)));
typedef unsigned int u32x2 __attribute__((ext_vector_type(2)));

__device__ __forceinline__ unsigned short f2bf(float f) {
    unsigned u = __builtin_bit_cast(unsigned, f);
    u += 0x7fffu + ((u >> 16) & 1u);
    return (unsigned short)(u >> 16);
}
__device__ __forceinline__ float bf2f(unsigned short s) {
    return __builtin_bit_cast(float, ((unsigned)s) << 16);
}

// ---------------- prep: fp32 -> bf16 weights ----------------
__global__ __launch_bounds__(256) void kprep(
    const float* __restrict__ w1, const float* __restrict__ w2, const float* __restrict__ w5,
    const float* __restrict__ b1, const float* __restrict__ b2,
    unsigned short* __restrict__ wcat, unsigned short* __restrict__ wb5,
    float* __restrict__ bcat)
{
    const int i = blockIdx.x * 256 + threadIdx.x;
    if (i < 384 * 64) {
        const int r = i >> 6;
        wcat[i] = f2bf(r < 192 ? w2[i] : w1[i - 192 * 64]);
    }
    if (i < 128 * 128) wb5[i] = f2bf(w5[i]);
    if (i < 384) bcat[i] = (i < 192) ? b2[i] : b1[i - 192];
}

// ---------------- zero the halo borders of all lqkv planes ----------------
__global__ __launch_bounds__(256) void kzero(unsigned short* __restrict__ lqkv)
{
    unsigned short* plane = lqkv + (size_t)blockIdx.x * PL;
    for (int i = threadIdx.x; i < 656; i += 256) {
        int idx;
        if (i < 144) {
            const int r = (i < 72) ? 0 : 65;
            idx = r * RS + (i % 72);
        } else {
            const int j = i - 144;
            const int r = 1 + (j >> 3);
            const int cs = j & 7;
            idx = r * RS + (cs < 4 ? cs : 64 + cs);
        }
        plane[idx] = 0;
    }
}

// ---------------- K1: LayerNorm + fc1/fc2 via MFMA + pooled K/V ----------------
__global__ __launch_bounds__(256) void k1_ln_fc(
    const float* __restrict__ x, const float* __restrict__ ng, const float* __restrict__ nb,
    const unsigned short* __restrict__ wcat, const float* __restrict__ bcat,
    float* __restrict__ gq, float* __restrict__ gkp, float* __restrict__ gvp,
    unsigned short* __restrict__ lqkv)
{
    __shared__ unsigned short xnT[64 * 128];   // [pixel][c] bf16, XOR-swizzled
    __shared__ float red[2][4][64];
    const int t = threadIdx.x;
    const int g = t >> 6;
    const int p = t & 63;
    const int bx = blockIdx.x;
    const int b = bx >> 6;
    const int h = bx & 63;
    const float* xrow = x + (size_t)b * 128 * HW + h * 64;

    float v[32];
    float s1 = 0.f, s2 = 0.f;
    #pragma unroll
    for (int i = 0; i < 32; ++i) {
        const int c = g * 32 + i;
        const float vv = xrow[(size_t)c * HW + p];
        v[i] = vv; s1 += vv; s2 += vv * vv;
    }
    red[0][g][p] = s1; red[1][g][p] = s2;
    __syncthreads();
    const float m   = (red[0][0][p] + red[0][1][p] + red[0][2][p] + red[0][3][p]) * (1.f / 128.f);
    const float var = (red[1][0][p] + red[1][1][p] + red[1][2][p] + red[1][3][p]) * (1.f / 128.f) - m * m;
    const float rstd = rsqrtf(var + 1e-5f);

    #pragma unroll
    for (int j = 0; j < 4; ++j) {
        u32x4 pk;
        #pragma unroll
        for (int q = 0; q < 4; ++q) {
            const int i0 = j * 8 + q * 2;
            const int c0 = g * 32 + i0;
            const float f0 = (v[i0]     - m) * rstd * ng[c0]     + nb[c0];
            const float f1 = (v[i0 + 1] - m) * rstd * ng[c0 + 1] + nb[c0 + 1];
            pk[q] = (unsigned)f2bf(f0) | ((unsigned)f2bf(f1) << 16);
        }
        const int colu = (g * 32 + j * 8) ^ ((p & 7) * 8);
        *reinterpret_cast<u32x4*>(&xnT[p * 128 + colu]) = pk;
    }
    __syncthreads();

    const int wid = g;
    const int lg = p >> 4, lr = p & 15;
    const int kbase = (wid >= 2) ? 64 : 0;

    bf16x8 afr[4][2];
    #pragma unroll
    for (int mt = 0; mt < 4; ++mt)
        #pragma unroll
        for (int kc = 0; kc < 2; ++kc) {
            const int pix = mt * 16 + lr;
            const int colu = (kbase + kc * 32 + lg * 8) ^ ((pix & 7) * 8);
            afr[mt][kc] = *reinterpret_cast<const bf16x8*>(&xnT[pix * 128 + colu]);
        }

    const int nbase = wid * 96;
    #pragma unroll
    for (int nt = 0; nt < 6; ++nt) {
        const int o0 = nbase + nt * 16;
        const int o  = o0 + lr;
        const float bias = bcat[o];
        f32x4 acc[4];
        #pragma unroll
        for (int mt = 0; mt < 4; ++mt) acc[mt] = f32x4{bias, bias, bias, bias};
        #pragma unroll
        for (int kc = 0; kc < 2; ++kc) {
            const bf16x8 bfr = *reinterpret_cast<const bf16x8*>(&wcat[(size_t)o * 64 + kc * 32 + lg * 8]);
            #pragma unroll
            for (int mt = 0; mt < 4; ++mt)
                acc[mt] = __builtin_amdgcn_mfma_f32_16x16x32_bf16(afr[mt][kc], bfr, acc[mt], 0, 0, 0);
        }
        if (o0 < 192) {
            // fc2 -> lqkv bf16 padded: [arr][(b*4+lh)*16+cl][(h+1)*72 + 4 + w]
            const int cc = o0 >> 6;
            const int lh2 = (o0 & 63) >> 4;
            unsigned short* dst = lqkv + (size_t)cc * APL
                                + (((size_t)b * 4 + lh2) * 16 + lr) * PL
                                + (size_t)(h + 1) * RS + 4;
            #pragma unroll
            for (int mt = 0; mt < 4; ++mt) {
                u32x2 pk;
                pk[0] = (unsigned)f2bf(acc[mt][0]) | ((unsigned)f2bf(acc[mt][1]) << 16);
                pk[1] = (unsigned)f2bf(acc[mt][2]) | ((unsigned)f2bf(acc[mt][3]) << 16);
                *reinterpret_cast<u32x2*>(&dst[mt * 16 + lg * 4]) = pk;
            }
        } else if (o0 < 256) {
            // fc1 q -> gq [b][gh][cg][n] f32
            const int gh = (o0 - 192) >> 4;
            float* dst = gq + (((size_t)b * 4 + gh) * 16) * HW;
            #pragma unroll
            for (int mt = 0; mt < 4; ++mt)
                *reinterpret_cast<f32x4*>(&dst[(size_t)lr * HW + h * 64 + mt * 16 + lg * 4]) = acc[mt];
        } else {
            // fc1 k,v -> pooled [b][gh][m][cg]
            const int kvsel = (o0 - 256) >> 6;
            const int gh = ((o0 - 256) & 63) >> 4;
            float* dst = (kvsel ? gvp : gkp) + (((size_t)b * 4 + gh) * 64 + (h >> 3) * 8) * 16;
            #pragma unroll
            for (int mt = 0; mt < 4; ++mt) {
                float s = acc[mt][0] + acc[mt][1] + acc[mt][2] + acc[mt][3];
                s += __shfl_xor(s, 16);
                if (!(p & 16))
                    atomicAdd(&dst[(2 * mt + (lg >> 1)) * 16 + lr], s * (1.f / 64.f));
            }
        }
    }
}

// ---------------- K2: global attention (64 pooled tokens), K/V in LDS ----------------
__global__ __launch_bounds__(256) void k2_attn(
    const float* __restrict__ gq, const float* __restrict__ gkp,
    const float* __restrict__ gvp, float* __restrict__ out)
{
    __shared__ float skv[2][64][16];
    const int t = threadIdx.x;
    const int bx = blockIdx.x;
    const int tile = bx & 15;
    const int bg = bx >> 4;
    const int b = bg >> 2;
    const int gh = bg & 3;
    for (int i = t; i < 1024; i += 256) {
        skv[0][i >> 4][i & 15] = gkp[(size_t)bg * 1024 + i];
        skv[1][i >> 4][i & 15] = gvp[(size_t)bg * 1024 + i];
    }
    __syncthreads();
    const int n = tile * 256 + t;
    const float* qp = gq + (size_t)bg * 16 * HW + n;
    float q[16];
    #pragma unroll
    for (int cg = 0; cg < 16; ++cg) q[cg] = qp[(size_t)cg * HW] * 0.125f;
    float s[64];
    #pragma unroll
    for (int mm = 0; mm < 64; ++mm) {
        float a = 0.f;
        #pragma unroll
        for (int cg = 0; cg < 16; ++cg) a = fmaf(q[cg], skv[0][mm][cg], a);
        s[mm] = a;
    }
    float mx = s[0];
    #pragma unroll
    for (int mm = 1; mm < 64; ++mm) mx = fmaxf(mx, s[mm]);
    float sum = 0.f;
    #pragma unroll
    for (int mm = 0; mm < 64; ++mm) { float e = __expf(s[mm] - mx); s[mm] = e; sum += e; }
    const float rs = 1.f / sum;
    float acc[16];
    #pragma unroll
    for (int cg = 0; cg < 16; ++cg) acc[cg] = 0.f;
    #pragma unroll
    for (int mm = 0; mm < 64; ++mm) {
        const float pm = s[mm];
        #pragma unroll
        for (int cg = 0; cg < 16; ++cg) acc[cg] = fmaf(pm, skv[1][mm][cg], acc[cg]);
    }
    float* op = out + ((size_t)b * 128 + 64 + gh * 16) * HW + n;
    #pragma unroll
    for (int cg = 0; cg < 16; ++cg) op[(size_t)cg * HW] = acc[cg] * rs;
}

// ---------------- K3: local branch, padded bf16 input, pipelined staging ----------------
__global__ __launch_bounds__(256) void k3_local(
    const unsigned short* __restrict__ lqkv,
    const float* __restrict__ qw, const float* __restrict__ qb,
    const float* __restrict__ kw, const float* __restrict__ kb,
    const float* __restrict__ vw, const float* __restrict__ vb,
    const float* __restrict__ w3, const float* __restrict__ b3,
    const float* __restrict__ w4, const float* __restrict__ b4,
    float* __restrict__ out)
{
    __shared__ float sb[3][4][6][LRS];   // 21888 B, one 4-channel chunk
    const int t = threadIdx.x;
    const int w = t & 63;
    const int rr = t >> 6;
    const int bx = blockIdx.x;
    const int htile = bx & 15;
    const int bl = bx >> 4;             // b*4+lh
    const int b = bl >> 2;
    const int lh = bl & 3;
    const int h0 = htile * 4;
    const int h = h0 + rr;

    // ---- decode 3 staging tasks/thread: 648 = 3arr x 4ch x 6row x 9(chunks of 8) ----
    bool ton[3];
    size_t tgoff[3];
    int tloff[3];
    #pragma unroll
    for (int k = 0; k < 3; ++k) {
        const int s = t + 256 * k;
        ton[k] = (s < 648);
        const int arr = s / 216;
        const int r1 = s - arr * 216;
        const int ch = r1 / 54;
        const int r2 = r1 - ch * 54;
        const int row = r2 / 9;
        const int ck = r2 - row * 9;
        tgoff[k] = (size_t)arr * APL + ((size_t)bl * 16 + ch) * PL
                 + (size_t)(h0 + row) * RS + ck * 8;
        tloff[k] = ((arr * 4 + ch) * 6 + row) * LRS + ck * 8;
    }
    float* sbf = &sb[0][0][0][0];

    float a[16], lvv[16];

    // prologue: stage chunk 0
    {
        u16x8 rg[3];
        #pragma unroll
        for (int k = 0; k < 3; ++k)
            if (ton[k]) rg[k] = *reinterpret_cast<const u16x8*>(lqkv + tgoff[k]);
        #pragma unroll
        for (int k = 0; k < 3; ++k)
            if (ton[k]) {
                f32x4 lo, hi;
                #pragma unroll
                for (int j = 0; j < 4; ++j) { lo[j] = bf2f(rg[k][j]); hi[j] = bf2f(rg[k][j + 4]); }
                *reinterpret_cast<f32x4*>(&sbf[tloff[k]])     = lo;
                *reinterpret_cast<f32x4*>(&sbf[tloff[k] + 4]) = hi;
            }
    }
    __syncthreads();

    #pragma unroll
    for (int c = 0; c < 4; ++c) {
        u16x8 rg[3];
        if (c < 3) {
            #pragma unroll
            for (int k = 0; k < 3; ++k)
                if (ton[k]) rg[k] = *reinterpret_cast<const u16x8*>(lqkv + tgoff[k] + (size_t)((c + 1) * 4) * PL);
        }
        // ---- compute chunk c from LDS (loads for c+1 in flight) ----
        #pragma unroll
        for (int ch = 0; ch < 4; ++ch) {
            const int cl = c * 4 + ch;
            float aq = qb[cl], ak = kb[cl], av = vb[cl];
            #pragma unroll
            for (int dy = 0; dy < 3; ++dy) {
                #pragma unroll
                for (int dx = 0; dx < 3; ++dx) {
                    const int wi = cl * 9 + dy * 3 + dx;
                    const int col = w + 3 + dx;
                    aq = fmaf(qw[wi], sb[0][ch][rr + dy][col], aq);
                    ak = fmaf(kw[wi], sb[1][ch][rr + dy][col], ak);
                    av = fmaf(vw[wi], sb[2][ch][rr + dy][col], av);
                }
            }
            a[cl] = aq * ak;
            lvv[cl] = av;
        }
        __syncthreads();            // everyone done reading chunk c
        if (c < 3) {
            #pragma unroll
            for (int k = 0; k < 3; ++k)
                if (ton[k]) {
                    f32x4 lo, hi;
                    #pragma unroll
                    for (int j = 0; j < 4; ++j) { lo[j] = bf2f(rg[k][j]); hi[j] = bf2f(rg[k][j + 4]); }
                    *reinterpret_cast<f32x4*>(&sbf[tloff[k]])     = lo;
                    *reinterpret_cast<f32x4*>(&sbf[tloff[k] + 4]) = hi;
                }
            __syncthreads();
        }
    }

    float a2[16];
    #pragma unroll
    for (int o = 0; o < 16; ++o) {
        float acc = b3[o];
        #pragma unroll
        for (int c2 = 0; c2 < 16; ++c2) acc = fmaf(w3[o * 16 + c2], a[c2], acc);
        a2[o] = acc / (1.f + __expf(-acc));
    }
    float* op = out + ((size_t)b * 128 + lh * 16) * HW + (size_t)h * 64 + w;
    #pragma unroll
    for (int o = 0; o < 16; ++o) {
        float acc = b4[o];
        #pragma unroll
        for (int c2 = 0; c2 < 16; ++c2) acc = fmaf(w4[o * 16 + c2], a2[c2], acc);
        const float z = acc * 8.f;
        const float e2 = __expf(-2.f * fabsf(z));
        float th = (1.f - e2) / (1.f + e2);
        th = copysignf(th, z);
        op[(size_t)o * HW] = th * lvv[o];
    }
}

// ---------------- K4: fc5 (128x128) via MFMA + residual, in-place ----------------
__global__ __launch_bounds__(256) void k4_fc5(
    const float* __restrict__ x, const unsigned short* __restrict__ wb5,
    const float* __restrict__ b5, float* __restrict__ out)
{
    __shared__ unsigned short xcT[64 * 128];
    const int t = threadIdx.x;
    const int g = t >> 6, p = t & 63;
    const int bx = blockIdx.x;
    const int b = bx >> 6, h = bx & 63;
    float* obase = out + (size_t)b * 128 * HW + h * 64;

    float v[32];
    #pragma unroll
    for (int i = 0; i < 32; ++i) v[i] = obase[(size_t)(g * 32 + i) * HW + p];
    #pragma unroll
    for (int j = 0; j < 4; ++j) {
        u32x4 pk;
        #pragma unroll
        for (int q = 0; q < 4; ++q) {
            const int i0 = j * 8 + q * 2;
            pk[q] = (unsigned)f2bf(v[i0]) | ((unsigned)f2bf(v[i0 + 1]) << 16);
        }
        const int colu = (g * 32 + j * 8) ^ ((p & 7) * 8);
        *reinterpret_cast<u32x4*>(&xcT[p * 128 + colu]) = pk;
    }
    __syncthreads();

    const int wid = g, lg = p >> 4, lr = p & 15;
    bf16x8 afr[4][4];
    #pragma unroll
    for (int mt = 0; mt < 4; ++mt)
        #pragma unroll
        for (int kc = 0; kc < 4; ++kc) {
            const int pix = mt * 16 + lr;
            const int colu = (kc * 32 + lg * 8) ^ ((pix & 7) * 8);
            afr[mt][kc] = *reinterpret_cast<const bf16x8*>(&xcT[pix * 128 + colu]);
        }
    const float* xrow = x + (size_t)b * 128 * HW + h * 64;
    #pragma unroll
    for (int nt = 0; nt < 2; ++nt) {
        const int o = wid * 32 + nt * 16 + lr;
        const float bias = b5[o];
        f32x4 acc[4];
        #pragma unroll
        for (int mt = 0; mt < 4; ++mt) acc[mt] = f32x4{bias, bias, bias, bias};
        #pragma unroll
        for (int kc = 0; kc < 4; ++kc) {
            const bf16x8 bfr = *reinterpret_cast<const bf16x8*>(&wb5[(size_t)o * 128 + kc * 32 + lg * 8]);
            #pragma unroll
            for (int mt = 0; mt < 4; ++mt)
                acc[mt] = __builtin_amdgcn_mfma_f32_16x16x32_bf16(afr[mt][kc], bfr, acc[mt], 0, 0, 0);
        }
        #pragma unroll
        for (int mt = 0; mt < 4; ++mt) {
            const size_t off = (size_t)o * HW + mt * 16 + lg * 4;
            const f32x4 xr = *reinterpret_cast<const f32x4*>(&xrow[off]);
            const f32x4 r = acc[mt] + xr;
            *reinterpret_cast<f32x4*>(&obase[off]) = r;
        }
    }
}

extern "C" void kernel_launch(void* const* d_in, const int* in_sizes, int n_in,
                              void* d_out, int out_size, void* d_ws, size_t ws_size,
                              hipStream_t stream) {
    const float* x  = (const float*)d_in[0];
    const float* ng = (const float*)d_in[1];
    const float* nb = (const float*)d_in[2];
    const float* w1 = (const float*)d_in[3];
    const float* b1 = (const float*)d_in[4];
    const float* w2 = (const float*)d_in[5];
    const float* b2 = (const float*)d_in[6];
    const float* qw = (const float*)d_in[7];
    const float* qb = (const float*)d_in[8];
    const float* kw = (const float*)d_in[9];
    const float* kb = (const float*)d_in[10];
    const float* vw = (const float*)d_in[11];
    const float* vb = (const float*)d_in[12];
    const float* w3 = (const float*)d_in[13];
    const float* b3 = (const float*)d_in[14];
    const float* w4 = (const float*)d_in[15];
    const float* b4 = (const float*)d_in[16];
    const float* w5 = (const float*)d_in[17];
    const float* b5 = (const float*)d_in[18];
    float* out = (float*)d_out;
    float* ws  = (float*)d_ws;

    float* gq  = ws;                                   // 8388608 f32  [b][gh][cg][n]
    float* gkp = gq  + 8388608;                        // 131072 f32   [b][gh][m][cg]
    float* gvp = gkp + 131072;                         // 131072 f32
    unsigned short* lqkv = (unsigned short*)(gvp + 131072);  // 3*2048*4752 bf16 padded
    unsigned short* wcat = lqkv + 3 * APL;             // 384*64 bf16 (rows 0..191=w2, 192..383=w1)
    unsigned short* wb5  = wcat + 384 * 64;            // 128*128 bf16
    float* bcat = (float*)(wb5 + 128 * 128);           // 384 f32 (b2|b1)

    kprep<<<96, 256, 0, stream>>>(w1, w2, w5, b1, b2, wcat, wb5, bcat);
    kzero<<<6144, 256, 0, stream>>>(lqkv);
    hipMemsetAsync(gkp, 0, 2 * 131072 * sizeof(float), stream);
    k1_ln_fc<<<2048, 256, 0, stream>>>(x, ng, nb, wcat, bcat, gq, gkp, gvp, lqkv);
    k2_attn<<<2048, 256, 0, stream>>>(gq, gkp, gvp, out);
    k3_local<<<2048, 256, 0, stream>>>(lqkv, qw, qb, kw, kb, vw, vb,
                                       w3, b3, w4, b4, out);
    k4_fc5<<<2048, 256, 0, stream>>>(x, wb5, b5, out);
}

// Round 8
// 301.682 us; speedup vs baseline: 1.8528x; 1.3641x over previous
//
#include <hip/hip_runtime.h>
#include <cstddef>

#define HW 4096
#define PL 4752            // padded plane: 66 rows x 72 cols (global)
#define RS 72
#define APL (2048 * 4752)  // per-array stride (2048 planes)

typedef short bf16x8 __attribute__((ext_vector_type(8)));
typedef unsigned short u16x8 __attribute__((ext_vector_type(8)));
typedef float f32x4 __attribute__((ext_vector_type(4)));
typedef unsigned int u32x4 __attribute__((ext_vector_type(4)));
typedef unsigned int u32x2 __attribute__((ext_vector_type(2)));

__device__ __forceinline__ unsigned short f2bf(float f) {
    unsigned u = __builtin_bit_cast(unsigned, f);
    u += 0x7fffu + ((u >> 16) & 1u);
    return (unsigned short)(u >> 16);
}
__device__ __forceinline__ float bf2f(unsigned short s) {
    return __builtin_bit_cast(float, ((unsigned)s) << 16);
}
// lane i <- lane i-1 (0 into lane 0): v_mov_dpp wave_shr:1
__device__ __forceinline__ float dpp_left(float x) {
    return __builtin_bit_cast(float,
        __builtin_amdgcn_update_dpp(0, __builtin_bit_cast(int, x), 0x138, 0xf, 0xf, false));
}
// lane i <- lane i+1 (0 into lane 63): v_mov_dpp wave_shl:1
__device__ __forceinline__ float dpp_right(float x) {
    return __builtin_bit_cast(float,
        __builtin_amdgcn_update_dpp(0, __builtin_bit_cast(int, x), 0x130, 0xf, 0xf, false));
}

// ---------------- prep: fp32 -> bf16 weights ----------------
__global__ __launch_bounds__(256) void kprep(
    const float* __restrict__ w1, const float* __restrict__ w2, const float* __restrict__ w5,
    const float* __restrict__ b1, const float* __restrict__ b2,
    unsigned short* __restrict__ wcat, unsigned short* __restrict__ wb5,
    float* __restrict__ bcat)
{
    const int i = blockIdx.x * 256 + threadIdx.x;
    if (i < 384 * 64) {
        const int r = i >> 6;
        wcat[i] = f2bf(r < 192 ? w2[i] : w1[i - 192 * 64]);
    }
    if (i < 128 * 128) wb5[i] = f2bf(w5[i]);
    if (i < 384) bcat[i] = (i < 192) ? b2[i] : b1[i - 192];
}

// ---------------- zero top/bottom halo rows of all lqkv planes ----------------
__global__ __launch_bounds__(256) void kzero(unsigned short* __restrict__ lqkv)
{
    unsigned short* plane = lqkv + (size_t)blockIdx.x * PL;
    const int i = threadIdx.x;
    if (i < 144) {
        const int r = (i < 72) ? 0 : 65;
        plane[r * RS + (i % 72)] = 0;
    }
}

// ---------------- K1: LayerNorm + fc1/fc2 via MFMA + pooled K/V ----------------
__global__ __launch_bounds__(256) void k1_ln_fc(
    const float* __restrict__ x, const float* __restrict__ ng, const float* __restrict__ nb,
    const unsigned short* __restrict__ wcat, const float* __restrict__ bcat,
    unsigned short* __restrict__ gqb, float* __restrict__ gkp, float* __restrict__ gvp,
    unsigned short* __restrict__ lqkv)
{
    __shared__ unsigned short xnT[64 * 128];   // [pixel][c] bf16, XOR-swizzled
    __shared__ float red[2][4][64];
    const int t = threadIdx.x;
    const int g = t >> 6;
    const int p = t & 63;
    const int bx = blockIdx.x;
    const int b = bx >> 6;
    const int h = bx & 63;
    const float* xrow = x + (size_t)b * 128 * HW + h * 64;

    float v[32];
    float s1 = 0.f, s2 = 0.f;
    #pragma unroll
    for (int i = 0; i < 32; ++i) {
        const int c = g * 32 + i;
        const float vv = xrow[(size_t)c * HW + p];
        v[i] = vv; s1 += vv; s2 += vv * vv;
    }
    red[0][g][p] = s1; red[1][g][p] = s2;
    __syncthreads();
    const float m   = (red[0][0][p] + red[0][1][p] + red[0][2][p] + red[0][3][p]) * (1.f / 128.f);
    const float var = (red[1][0][p] + red[1][1][p] + red[1][2][p] + red[1][3][p]) * (1.f / 128.f) - m * m;
    const float rstd = rsqrtf(var + 1e-5f);

    #pragma unroll
    for (int j = 0; j < 4; ++j) {
        u32x4 pk;
        #pragma unroll
        for (int q = 0; q < 4; ++q) {
            const int i0 = j * 8 + q * 2;
            const int c0 = g * 32 + i0;
            const float f0 = (v[i0]     - m) * rstd * ng[c0]     + nb[c0];
            const float f1 = (v[i0 + 1] - m) * rstd * ng[c0 + 1] + nb[c0 + 1];
            pk[q] = (unsigned)f2bf(f0) | ((unsigned)f2bf(f1) << 16);
        }
        const int colu = (g * 32 + j * 8) ^ ((p & 7) * 8);
        *reinterpret_cast<u32x4*>(&xnT[p * 128 + colu]) = pk;
    }
    __syncthreads();

    const int wid = g;
    const int lg = p >> 4, lr = p & 15;
    const int kbase = (wid >= 2) ? 64 : 0;

    bf16x8 afr[4][2];
    #pragma unroll
    for (int mt = 0; mt < 4; ++mt)
        #pragma unroll
        for (int kc = 0; kc < 2; ++kc) {
            const int pix = mt * 16 + lr;
            const int colu = (kbase + kc * 32 + lg * 8) ^ ((pix & 7) * 8);
            afr[mt][kc] = *reinterpret_cast<const bf16x8*>(&xnT[pix * 128 + colu]);
        }

    const int nbase = wid * 96;
    #pragma unroll
    for (int nt = 0; nt < 6; ++nt) {
        const int o0 = nbase + nt * 16;
        const int o  = o0 + lr;
        const float bias = bcat[o];
        f32x4 acc[4];
        #pragma unroll
        for (int mt = 0; mt < 4; ++mt) acc[mt] = f32x4{bias, bias, bias, bias};
        #pragma unroll
        for (int kc = 0; kc < 2; ++kc) {
            const bf16x8 bfr = *reinterpret_cast<const bf16x8*>(&wcat[(size_t)o * 64 + kc * 32 + lg * 8]);
            #pragma unroll
            for (int mt = 0; mt < 4; ++mt)
                acc[mt] = __builtin_amdgcn_mfma_f32_16x16x32_bf16(afr[mt][kc], bfr, acc[mt], 0, 0, 0);
        }
        if (o0 < 192) {
            // fc2 -> lqkv bf16 padded: [arr][(b*4+lh)*16+cl][(h+1)*72 + 4 + w]
            const int cc = o0 >> 6;
            const int lh2 = (o0 & 63) >> 4;
            unsigned short* dst = lqkv + (size_t)cc * APL
                                + (((size_t)b * 4 + lh2) * 16 + lr) * PL
                                + (size_t)(h + 1) * RS + 4;
            #pragma unroll
            for (int mt = 0; mt < 4; ++mt) {
                u32x2 pk;
                pk[0] = (unsigned)f2bf(acc[mt][0]) | ((unsigned)f2bf(acc[mt][1]) << 16);
                pk[1] = (unsigned)f2bf(acc[mt][2]) | ((unsigned)f2bf(acc[mt][3]) << 16);
                *reinterpret_cast<u32x2*>(&dst[mt * 16 + lg * 4]) = pk;
            }
        } else if (o0 < 256) {
            // fc1 q -> gq bf16 [b][gh][cg][n]
            const int gh = (o0 - 192) >> 4;
            unsigned short* dst = gqb + (((size_t)b * 4 + gh) * 16) * HW;
            #pragma unroll
            for (int mt = 0; mt < 4; ++mt) {
                u32x2 pk;
                pk[0] = (unsigned)f2bf(acc[mt][0]) | ((unsigned)f2bf(acc[mt][1]) << 16);
                pk[1] = (unsigned)f2bf(acc[mt][2]) | ((unsigned)f2bf(acc[mt][3]) << 16);
                *reinterpret_cast<u32x2*>(&dst[(size_t)lr * HW + h * 64 + mt * 16 + lg * 4]) = pk;
            }
        } else {
            // fc1 k,v -> pooled [b][gh][m][cg] f32 via atomics
            const int kvsel = (o0 - 256) >> 6;
            const int gh = ((o0 - 256) & 63) >> 4;
            float* dst = (kvsel ? gvp : gkp) + (((size_t)b * 4 + gh) * 64 + (h >> 3) * 8) * 16;
            #pragma unroll
            for (int mt = 0; mt < 4; ++mt) {
                float s = acc[mt][0] + acc[mt][1] + acc[mt][2] + acc[mt][3];
                s += __shfl_xor(s, 16);
                if (!(p & 16))
                    atomicAdd(&dst[(2 * mt + (lg >> 1)) * 16 + lr], s * (1.f / 64.f));
            }
        }
    }
}

// ---------------- K2: global attention (64 pooled tokens), K/V in LDS ----------------
__global__ __launch_bounds__(256) void k2_attn(
    const unsigned short* __restrict__ gqb, const float* __restrict__ gkp,
    const float* __restrict__ gvp, unsigned short* __restrict__ xc)
{
    __shared__ float skv[2][64][16];
    const int t = threadIdx.x;
    const int bx = blockIdx.x;
    const int tile = bx & 15;
    const int bg = bx >> 4;
    const int b = bg >> 2;
    const int gh = bg & 3;
    for (int i = t; i < 1024; i += 256) {
        skv[0][i >> 4][i & 15] = gkp[(size_t)bg * 1024 + i];
        skv[1][i >> 4][i & 15] = gvp[(size_t)bg * 1024 + i];
    }
    __syncthreads();
    const int n = tile * 256 + t;
    const unsigned short* qp = gqb + (size_t)bg * 16 * HW + n;
    float q[16];
    #pragma unroll
    for (int cg = 0; cg < 16; ++cg) q[cg] = bf2f(qp[(size_t)cg * HW]) * 0.125f;
    float s[64];
    #pragma unroll
    for (int mm = 0; mm < 64; ++mm) {
        float a = 0.f;
        #pragma unroll
        for (int cg = 0; cg < 16; ++cg) a = fmaf(q[cg], skv[0][mm][cg], a);
        s[mm] = a;
    }
    float mx = s[0];
    #pragma unroll
    for (int mm = 1; mm < 64; ++mm) mx = fmaxf(mx, s[mm]);
    float sum = 0.f;
    #pragma unroll
    for (int mm = 0; mm < 64; ++mm) { float e = __expf(s[mm] - mx); s[mm] = e; sum += e; }
    const float rs = 1.f / sum;
    float acc[16];
    #pragma unroll
    for (int cg = 0; cg < 16; ++cg) acc[cg] = 0.f;
    #pragma unroll
    for (int mm = 0; mm < 64; ++mm) {
        const float pm = s[mm];
        #pragma unroll
        for (int cg = 0; cg < 16; ++cg) acc[cg] = fmaf(pm, skv[1][mm][cg], acc[cg]);
    }
    unsigned short* op = xc + ((size_t)b * 128 + 64 + gh * 16) * HW + n;  // xg ch 64..127
    #pragma unroll
    for (int cg = 0; cg < 16; ++cg) op[(size_t)cg * HW] = f2bf(acc[cg] * rs);
}

// ---------------- K3: local branch, DPP lane-shift conv, no LDS ----------------
__global__ __launch_bounds__(256, 4) void k3_local(
    const unsigned short* __restrict__ lqkv,
    const float* __restrict__ qw, const float* __restrict__ qb,
    const float* __restrict__ kw, const float* __restrict__ kb,
    const float* __restrict__ vw, const float* __restrict__ vb,
    const float* __restrict__ w3, const float* __restrict__ b3,
    const float* __restrict__ w4, const float* __restrict__ b4,
    unsigned short* __restrict__ xc)
{
    const int t = threadIdx.x;
    const int w = t & 63;
    const int rr = t >> 6;
    const int bx = blockIdx.x;
    const int htile = bx & 15;
    const int bl = bx >> 4;             // b*4+lh
    const int b = bl >> 2;
    const int lh = bl & 3;
    const int h = htile * 4 + rr;

    float a[16], lvv[16];
    #pragma unroll
    for (int cl = 0; cl < 16; ++cl) {
        // padded rows h, h+1, h+2 = image rows h-1, h, h+1; col 4+w
        const size_t pb = ((size_t)bl * 16 + cl) * PL + (size_t)h * RS + 4 + w;
        float aq = qb[cl], ak = kb[cl], av = vb[cl];
        #pragma unroll
        for (int dy = 0; dy < 3; ++dy) {
            const size_t idx = pb + (size_t)dy * RS;
            const float cq = bf2f(lqkv[idx]);
            const float ck = bf2f(lqkv[idx + APL]);
            const float cv = bf2f(lqkv[idx + 2 * APL]);
            const float lq = dpp_left(cq),  rq = dpp_right(cq);
            const float lk = dpp_left(ck),  rk = dpp_right(ck);
            const float lv = dpp_left(cv),  rv = dpp_right(cv);
            const int wi = cl * 9 + dy * 3;
            aq = fmaf(qw[wi], lq, aq); aq = fmaf(qw[wi + 1], cq, aq); aq = fmaf(qw[wi + 2], rq, aq);
            ak = fmaf(kw[wi], lk, ak); ak = fmaf(kw[wi + 1], ck, ak); ak = fmaf(kw[wi + 2], rk, ak);
            av = fmaf(vw[wi], lv, av); av = fmaf(vw[wi + 1], cv, av); av = fmaf(vw[wi + 2], rv, av);
        }
        a[cl] = aq * ak;
        lvv[cl] = av;
    }

    float a2[16];
    #pragma unroll
    for (int o = 0; o < 16; ++o) {
        float acc = b3[o];
        #pragma unroll
        for (int c2 = 0; c2 < 16; ++c2) acc = fmaf(w3[o * 16 + c2], a[c2], acc);
        a2[o] = acc / (1.f + __expf(-acc));
    }
    unsigned short* op = xc + ((size_t)b * 128 + lh * 16) * HW + (size_t)h * 64 + w;  // xl ch 0..63
    #pragma unroll
    for (int o = 0; o < 16; ++o) {
        float acc = b4[o];
        #pragma unroll
        for (int c2 = 0; c2 < 16; ++c2) acc = fmaf(w4[o * 16 + c2], a2[c2], acc);
        const float z = acc * 8.f;
        const float e2 = __expf(-2.f * fabsf(z));
        float th = (1.f - e2) / (1.f + e2);
        th = copysignf(th, z);
        op[(size_t)o * HW] = f2bf(th * lvv[o]);
    }
}

// ---------------- K4: fc5 (128x128) via MFMA + residual ----------------
__global__ __launch_bounds__(256) void k4_fc5(
    const float* __restrict__ x, const unsigned short* __restrict__ xc,
    const unsigned short* __restrict__ wb5,
    const float* __restrict__ b5, float* __restrict__ out)
{
    __shared__ unsigned short xcT[64 * 128];
    const int t = threadIdx.x;
    const int g = t >> 6, p = t & 63;
    const int bx = blockIdx.x;
    const int b = bx >> 6, h = bx & 63;
    const unsigned short* cbase = xc + (size_t)b * 128 * HW + h * 64;

    unsigned short vv[32];
    #pragma unroll
    for (int i = 0; i < 32; ++i) vv[i] = cbase[(size_t)(g * 32 + i) * HW + p];
    #pragma unroll
    for (int j = 0; j < 4; ++j) {
        u32x4 pk;
        #pragma unroll
        for (int q = 0; q < 4; ++q) {
            const int i0 = j * 8 + q * 2;
            pk[q] = (unsigned)vv[i0] | ((unsigned)vv[i0 + 1] << 16);
        }
        const int colu = (g * 32 + j * 8) ^ ((p & 7) * 8);
        *reinterpret_cast<u32x4*>(&xcT[p * 128 + colu]) = pk;
    }
    __syncthreads();

    const int wid = g, lg = p >> 4, lr = p & 15;
    bf16x8 afr[4][4];
    #pragma unroll
    for (int mt = 0; mt < 4; ++mt)
        #pragma unroll
        for (int kc = 0; kc < 4; ++kc) {
            const int pix = mt * 16 + lr;
            const int colu = (kc * 32 + lg * 8) ^ ((pix & 7) * 8);
            afr[mt][kc] = *reinterpret_cast<const bf16x8*>(&xcT[pix * 128 + colu]);
        }
    const float* xrow = x + (size_t)b * 128 * HW + h * 64;
    float* obase = out + (size_t)b * 128 * HW + h * 64;
    #pragma unroll
    for (int nt = 0; nt < 2; ++nt) {
        const int o = wid * 32 + nt * 16 + lr;
        const float bias = b5[o];
        f32x4 acc[4];
        #pragma unroll
        for (int mt = 0; mt < 4; ++mt) acc[mt] = f32x4{bias, bias, bias, bias};
        #pragma unroll
        for (int kc = 0; kc < 4; ++kc) {
            const bf16x8 bfr = *reinterpret_cast<const bf16x8*>(&wb5[(size_t)o * 128 + kc * 32 + lg * 8]);
            #pragma unroll
            for (int mt = 0; mt < 4; ++mt)
                acc[mt] = __builtin_amdgcn_mfma_f32_16x16x32_bf16(afr[mt][kc], bfr, acc[mt], 0, 0, 0);
        }
        #pragma unroll
        for (int mt = 0; mt < 4; ++mt) {
            const size_t off = (size_t)o * HW + mt * 16 + lg * 4;
            const f32x4 xr = *reinterpret_cast<const f32x4*>(&xrow[off]);
            const f32x4 r = acc[mt] + xr;
            *reinterpret_cast<f32x4*>(&obase[off]) = r;
        }
    }
}

extern "C" void kernel_launch(void* const* d_in, const int* in_sizes, int n_in,
                              void* d_out, int out_size, void* d_ws, size_t ws_size,
                              hipStream_t stream) {
    const float* x  = (const float*)d_in[0];
    const float* ng = (const float*)d_in[1];
    const float* nb = (const float*)d_in[2];
    const float* w1 = (const float*)d_in[3];
    const float* b1 = (const float*)d_in[4];
    const float* w2 = (const float*)d_in[5];
    const float* b2 = (const float*)d_in[6];
    const float* qw = (const float*)d_in[7];
    const float* qb = (const float*)d_in[8];
    const float* kw = (const float*)d_in[9];
    const float* kb = (const float*)d_in[10];
    const float* vw = (const float*)d_in[11];
    const float* vb = (const float*)d_in[12];
    const float* w3 = (const float*)d_in[13];
    const float* b3 = (const float*)d_in[14];
    const float* w4 = (const float*)d_in[15];
    const float* b4 = (const float*)d_in[16];
    const float* w5 = (const float*)d_in[17];
    const float* b5 = (const float*)d_in[18];
    float* out = (float*)d_out;

    unsigned short* gqb  = (unsigned short*)d_ws;       // 8388608 bf16 [b][gh][cg][n]
    float* gkp = (float*)(gqb + 8388608);               // 131072 f32   [b][gh][m][cg]
    float* gvp = gkp + 131072;                          // 131072 f32
    unsigned short* lqkv = (unsigned short*)(gvp + 131072);  // 3*APL bf16 padded planes
    unsigned short* xc   = lqkv + 3 * APL;              // 16777216 bf16 [b][c][HW]
    unsigned short* wcat = xc + 16777216;               // 384*64 bf16
    unsigned short* wb5  = wcat + 384 * 64;             // 128*128 bf16
    float* bcat = (float*)(wb5 + 128 * 128);            // 384 f32 (b2|b1)

    kprep<<<96, 256, 0, stream>>>(w1, w2, w5, b1, b2, wcat, wb5, bcat);
    kzero<<<6144, 256, 0, stream>>>(lqkv);
    hipMemsetAsync(gkp, 0, 2 * 131072 * sizeof(float), stream);
    k1_ln_fc<<<2048, 256, 0, stream>>>(x, ng, nb, wcat, bcat, gqb, gkp, gvp, lqkv);
    k2_attn<<<2048, 256, 0, stream>>>(gqb, gkp, gvp, xc);
    k3_local<<<2048, 256, 0, stream>>>(lqkv, qw, qb, kw, kb, vw, vb,
                                       w3, b3, w4, b4, xc);
    k4_fc5<<<2048, 256, 0, stream>>>(x, xc, wb5, b5, out);
}

// Round 9
// 292.031 us; speedup vs baseline: 1.9140x; 1.0330x over previous
//
#include <hip/hip_runtime.h>
#include <cstddef>

#define HW 4096
#define PL 4224            // padded plane: 66 rows x 64 cols (row halo only)
#define APL (2048 * 4224)  // per-array stride (2048 planes)

typedef short bf16x8 __attribute__((ext_vector_type(8)));
typedef unsigned short u16x8 __attribute__((ext_vector_type(8)));
typedef float f32x4 __attribute__((ext_vector_type(4)));
typedef unsigned int u32x4 __attribute__((ext_vector_type(4)));
typedef unsigned int u32x2 __attribute__((ext_vector_type(2)));

__device__ __forceinline__ unsigned short f2bf(float f) {
    unsigned u = __builtin_bit_cast(unsigned, f);
    u += 0x7fffu + ((u >> 16) & 1u);
    return (unsigned short)(u >> 16);
}
__device__ __forceinline__ float bf2f(unsigned short s) {
    return __builtin_bit_cast(float, ((unsigned)s) << 16);
}
// lane i <- lane i-1 (0 into lane 0): v_mov_dpp wave_shr:1
__device__ __forceinline__ float dpp_left(float x) {
    return __builtin_bit_cast(float,
        __builtin_amdgcn_update_dpp(0, __builtin_bit_cast(int, x), 0x138, 0xf, 0xf, false));
}
// lane i <- lane i+1 (0 into lane 63): v_mov_dpp wave_shl:1
__device__ __forceinline__ float dpp_right(float x) {
    return __builtin_bit_cast(float,
        __builtin_amdgcn_update_dpp(0, __builtin_bit_cast(int, x), 0x130, 0xf, 0xf, false));
}

// ---------------- prep: fp32 -> bf16 weights ----------------
__global__ __launch_bounds__(256) void kprep(
    const float* __restrict__ w1, const float* __restrict__ w2, const float* __restrict__ w5,
    const float* __restrict__ b1, const float* __restrict__ b2,
    unsigned short* __restrict__ wcat, unsigned short* __restrict__ wb5,
    float* __restrict__ bcat)
{
    const int i = blockIdx.x * 256 + threadIdx.x;
    if (i < 384 * 64) {
        const int r = i >> 6;
        wcat[i] = f2bf(r < 192 ? w2[i] : w1[i - 192 * 64]);
    }
    if (i < 128 * 128) wb5[i] = f2bf(w5[i]);
    if (i < 384) bcat[i] = (i < 192) ? b2[i] : b1[i - 192];
}

// ---------------- K1: LayerNorm + fc1/fc2 via MFMA + pooled K/V ----------------
__global__ __launch_bounds__(256) void k1_ln_fc(
    const float* __restrict__ x, const float* __restrict__ ng, const float* __restrict__ nb,
    const unsigned short* __restrict__ wcat, const float* __restrict__ bcat,
    unsigned short* __restrict__ gqb, float* __restrict__ gkp, float* __restrict__ gvp,
    unsigned short* __restrict__ lqkv)
{
    __shared__ unsigned int xs[128][33];       // [c][pixel-pair] bf16x2, padded rows
    __shared__ unsigned short xnT[64 * 128];   // [pixel][c] bf16, XOR-swizzled
    __shared__ float red[2][4][64];
    const int t = threadIdx.x;
    const int g = t >> 6;
    const int p = t & 63;
    const int bx = blockIdx.x;
    const int b = bx >> 6;
    const int h = bx & 63;
    const float* xbase = x + (size_t)b * 128 * HW + h * 64;

    // ---- stage x (vectorized 16B loads) -> bf16 LDS [c][64] ----
    #pragma unroll
    for (int i = 0; i < 8; ++i) {
        const int idx = t + i * 256;           // 0..2047
        const int c = idx >> 4, seg = idx & 15;
        const f32x4 v4 = *reinterpret_cast<const f32x4*>(&xbase[(size_t)c * HW + seg * 4]);
        xs[c][seg * 2]     = (unsigned)f2bf(v4[0]) | ((unsigned)f2bf(v4[1]) << 16);
        xs[c][seg * 2 + 1] = (unsigned)f2bf(v4[2]) | ((unsigned)f2bf(v4[3]) << 16);
    }
    __syncthreads();

    // ---- LN sums for pixel p over this wave's 32 channels ----
    float v[32];
    float s1 = 0.f, s2 = 0.f;
    #pragma unroll
    for (int i = 0; i < 32; ++i) {
        const int c = g * 32 + i;
        const unsigned wv = xs[c][p >> 1];
        const float vv = bf2f((unsigned short)((p & 1) ? (wv >> 16) : (wv & 0xffff)));
        v[i] = vv; s1 += vv; s2 += vv * vv;
    }
    red[0][g][p] = s1; red[1][g][p] = s2;
    __syncthreads();
    const float m   = (red[0][0][p] + red[0][1][p] + red[0][2][p] + red[0][3][p]) * (1.f / 128.f);
    const float var = (red[1][0][p] + red[1][1][p] + red[1][2][p] + red[1][3][p]) * (1.f / 128.f) - m * m;
    const float rstd = rsqrtf(var + 1e-5f);

    #pragma unroll
    for (int j = 0; j < 4; ++j) {
        u32x4 pk;
        #pragma unroll
        for (int q = 0; q < 4; ++q) {
            const int i0 = j * 8 + q * 2;
            const int c0 = g * 32 + i0;
            const float f0 = (v[i0]     - m) * rstd * ng[c0]     + nb[c0];
            const float f1 = (v[i0 + 1] - m) * rstd * ng[c0 + 1] + nb[c0 + 1];
            pk[q] = (unsigned)f2bf(f0) | ((unsigned)f2bf(f1) << 16);
        }
        const int colu = (g * 32 + j * 8) ^ ((p & 7) * 8);
        *reinterpret_cast<u32x4*>(&xnT[p * 128 + colu]) = pk;
    }
    __syncthreads();

    const int wid = g;
    const int lg = p >> 4, lr = p & 15;
    const int kbase = (wid >= 2) ? 64 : 0;

    bf16x8 afr[4][2];
    #pragma unroll
    for (int mt = 0; mt < 4; ++mt)
        #pragma unroll
        for (int kc = 0; kc < 2; ++kc) {
            const int pix = mt * 16 + lr;
            const int colu = (kbase + kc * 32 + lg * 8) ^ ((pix & 7) * 8);
            afr[mt][kc] = *reinterpret_cast<const bf16x8*>(&xnT[pix * 128 + colu]);
        }

    const int nbase = wid * 96;
    #pragma unroll
    for (int nt = 0; nt < 6; ++nt) {
        const int o0 = nbase + nt * 16;
        const int o  = o0 + lr;
        const float bias = bcat[o];
        f32x4 acc[4];
        #pragma unroll
        for (int mt = 0; mt < 4; ++mt) acc[mt] = f32x4{bias, bias, bias, bias};
        #pragma unroll
        for (int kc = 0; kc < 2; ++kc) {
            const bf16x8 bfr = *reinterpret_cast<const bf16x8*>(&wcat[(size_t)o * 64 + kc * 32 + lg * 8]);
            #pragma unroll
            for (int mt = 0; mt < 4; ++mt)
                acc[mt] = __builtin_amdgcn_mfma_f32_16x16x32_bf16(afr[mt][kc], bfr, acc[mt], 0, 0, 0);
        }
        if (o0 < 192) {
            // fc2 -> lqkv bf16 row-padded: [arr][(b*4+lh)*16+cl][(h+1)*64 + w]
            const int cc = o0 >> 6;
            const int lh2 = (o0 & 63) >> 4;
            unsigned short* dst = lqkv + (size_t)cc * APL
                                + (((size_t)b * 4 + lh2) * 16 + lr) * PL
                                + (size_t)(h + 1) * 64;
            #pragma unroll
            for (int mt = 0; mt < 4; ++mt) {
                u32x2 pk;
                pk[0] = (unsigned)f2bf(acc[mt][0]) | ((unsigned)f2bf(acc[mt][1]) << 16);
                pk[1] = (unsigned)f2bf(acc[mt][2]) | ((unsigned)f2bf(acc[mt][3]) << 16);
                *reinterpret_cast<u32x2*>(&dst[mt * 16 + lg * 4]) = pk;
            }
        } else if (o0 < 256) {
            // fc1 q -> gq bf16 [b][gh][cg][n]
            const int gh = (o0 - 192) >> 4;
            unsigned short* dst = gqb + (((size_t)b * 4 + gh) * 16) * HW;
            #pragma unroll
            for (int mt = 0; mt < 4; ++mt) {
                u32x2 pk;
                pk[0] = (unsigned)f2bf(acc[mt][0]) | ((unsigned)f2bf(acc[mt][1]) << 16);
                pk[1] = (unsigned)f2bf(acc[mt][2]) | ((unsigned)f2bf(acc[mt][3]) << 16);
                *reinterpret_cast<u32x2*>(&dst[(size_t)lr * HW + h * 64 + mt * 16 + lg * 4]) = pk;
            }
        } else {
            // fc1 k,v -> pooled [b][gh][m][cg] f32 via atomics
            const int kvsel = (o0 - 256) >> 6;
            const int gh = ((o0 - 256) & 63) >> 4;
            float* dst = (kvsel ? gvp : gkp) + (((size_t)b * 4 + gh) * 64 + (h >> 3) * 8) * 16;
            #pragma unroll
            for (int mt = 0; mt < 4; ++mt) {
                float s = acc[mt][0] + acc[mt][1] + acc[mt][2] + acc[mt][3];
                s += __shfl_xor(s, 16);
                if (!(p & 16))
                    atomicAdd(&dst[(2 * mt + (lg >> 1)) * 16 + lr], s * (1.f / 64.f));
            }
        }
    }

    // ---- halo rows: blocks h==0 / h==63 zero rows 0 / 65 of this b's 192 planes ----
    if (h == 0 || h == 63) {
        const size_t rowoff = (h == 0) ? 0 : (size_t)65 * 64;
        for (int i = t; i < 192 * 8; i += 256) {
            const int pl2 = i >> 3, sect = i & 7;
            const int cc = pl2 >> 6, ch = pl2 & 63;
            const u32x4 z = {0, 0, 0, 0};
            *reinterpret_cast<u32x4*>(
                &lqkv[(size_t)cc * APL + ((size_t)b * 64 + ch) * PL + rowoff + sect * 8]) = z;
        }
    }
}

// ---------------- K2: global attention (64 pooled tokens), K/V in LDS ----------------
__global__ __launch_bounds__(256) void k2_attn(
    const unsigned short* __restrict__ gqb, const float* __restrict__ gkp,
    const float* __restrict__ gvp, unsigned short* __restrict__ xc)
{
    __shared__ float skv[2][64][16];
    const int t = threadIdx.x;
    const int bx = blockIdx.x;
    const int tile = bx & 15;
    const int bg = bx >> 4;
    const int b = bg >> 2;
    const int gh = bg & 3;
    for (int i = t; i < 1024; i += 256) {
        skv[0][i >> 4][i & 15] = gkp[(size_t)bg * 1024 + i];
        skv[1][i >> 4][i & 15] = gvp[(size_t)bg * 1024 + i];
    }
    __syncthreads();
    const int n = tile * 256 + t;
    const unsigned short* qp = gqb + (size_t)bg * 16 * HW + n;
    float q[16];
    #pragma unroll
    for (int cg = 0; cg < 16; ++cg) q[cg] = bf2f(qp[(size_t)cg * HW]) * 0.125f;
    float s[64];
    #pragma unroll
    for (int mm = 0; mm < 64; ++mm) {
        float a = 0.f;
        #pragma unroll
        for (int cg = 0; cg < 16; ++cg) a = fmaf(q[cg], skv[0][mm][cg], a);
        s[mm] = a;
    }
    float mx = s[0];
    #pragma unroll
    for (int mm = 1; mm < 64; ++mm) mx = fmaxf(mx, s[mm]);
    float sum = 0.f;
    #pragma unroll
    for (int mm = 0; mm < 64; ++mm) { float e = __expf(s[mm] - mx); s[mm] = e; sum += e; }
    const float rs = 1.f / sum;
    float acc[16];
    #pragma unroll
    for (int cg = 0; cg < 16; ++cg) acc[cg] = 0.f;
    #pragma unroll
    for (int mm = 0; mm < 64; ++mm) {
        const float pm = s[mm];
        #pragma unroll
        for (int cg = 0; cg < 16; ++cg) acc[cg] = fmaf(pm, skv[1][mm][cg], acc[cg]);
    }
    // xg -> xc[b][n][64 + gh*16 + cg]
    unsigned short* op = xc + ((size_t)b * HW + n) * 128 + 64 + gh * 16;
    u16x8 w0, w1;
    #pragma unroll
    for (int j = 0; j < 8; ++j) { w0[j] = f2bf(acc[j] * rs); w1[j] = f2bf(acc[j + 8] * rs); }
    *reinterpret_cast<u16x8*>(op) = w0;
    *reinterpret_cast<u16x8*>(op + 8) = w1;
}

// ---------------- K3: local branch, DPP lane-shift conv, no LDS ----------------
__global__ __launch_bounds__(256, 4) void k3_local(
    const unsigned short* __restrict__ lqkv,
    const float* __restrict__ qw, const float* __restrict__ qb,
    const float* __restrict__ kw, const float* __restrict__ kb,
    const float* __restrict__ vw, const float* __restrict__ vb,
    const float* __restrict__ w3, const float* __restrict__ b3,
    const float* __restrict__ w4, const float* __restrict__ b4,
    unsigned short* __restrict__ xc)
{
    const int t = threadIdx.x;
    const int w = t & 63;
    const int rr = t >> 6;
    const int bx = blockIdx.x;
    const int htile = bx & 15;
    const int bl = bx >> 4;             // b*4+lh
    const int b = bl >> 2;
    const int lh = bl & 3;
    const int h = htile * 4 + rr;

    float a[16], lvv[16];
    #pragma unroll
    for (int cl = 0; cl < 16; ++cl) {
        // padded rows h, h+1, h+2 = image rows h-1, h, h+1
        const size_t pb = ((size_t)bl * 16 + cl) * PL + (size_t)h * 64 + w;
        float aq = qb[cl], ak = kb[cl], av = vb[cl];
        #pragma unroll
        for (int dy = 0; dy < 3; ++dy) {
            const size_t idx = pb + (size_t)dy * 64;
            const float cq = bf2f(lqkv[idx]);
            const float ck = bf2f(lqkv[idx + APL]);
            const float cv = bf2f(lqkv[idx + 2 * APL]);
            const float lq = dpp_left(cq),  rq = dpp_right(cq);
            const float lk = dpp_left(ck),  rk = dpp_right(ck);
            const float lv = dpp_left(cv),  rv = dpp_right(cv);
            const int wi = cl * 9 + dy * 3;
            aq = fmaf(qw[wi], lq, aq); aq = fmaf(qw[wi + 1], cq, aq); aq = fmaf(qw[wi + 2], rq, aq);
            ak = fmaf(kw[wi], lk, ak); ak = fmaf(kw[wi + 1], ck, ak); ak = fmaf(kw[wi + 2], rk, ak);
            av = fmaf(vw[wi], lv, av); av = fmaf(vw[wi + 1], cv, av); av = fmaf(vw[wi + 2], rv, av);
        }
        a[cl] = aq * ak;
        lvv[cl] = av;
    }

    float a2[16];
    #pragma unroll
    for (int o = 0; o < 16; ++o) {
        float acc = b3[o];
        #pragma unroll
        for (int c2 = 0; c2 < 16; ++c2) acc = fmaf(w3[o * 16 + c2], a[c2], acc);
        a2[o] = acc / (1.f + __expf(-acc));
    }
    u16x8 r0, r1;
    #pragma unroll
    for (int o = 0; o < 16; ++o) {
        float acc = b4[o];
        #pragma unroll
        for (int c2 = 0; c2 < 16; ++c2) acc = fmaf(w4[o * 16 + c2], a2[c2], acc);
        const float z = acc * 8.f;
        const float e2 = __expf(-2.f * fabsf(z));
        float th = (1.f - e2) / (1.f + e2);
        th = copysignf(th, z);
        const unsigned short rbf = f2bf(th * lvv[o]);
        if (o < 8) r0[o] = rbf; else r1[o - 8] = rbf;
    }
    // xl -> xc[b][n][lh*16 + o]
    unsigned short* op = xc + ((size_t)b * HW + h * 64 + w) * 128 + lh * 16;
    *reinterpret_cast<u16x8*>(op) = r0;
    *reinterpret_cast<u16x8*>(op + 8) = r1;
}

// ---------------- K4: fc5 (128x128) via MFMA + residual, direct A loads ----------------
__global__ __launch_bounds__(256) void k4_fc5(
    const float* __restrict__ x, const unsigned short* __restrict__ xc,
    const unsigned short* __restrict__ wb5,
    const float* __restrict__ b5, float* __restrict__ out)
{
    const int t = threadIdx.x;
    const int g = t >> 6, p = t & 63;
    const int bx = blockIdx.x;
    const int b = bx >> 6, h = bx & 63;
    const int wid = g, lg = p >> 4, lr = p & 15;

    // A fragments directly from xc [b][n][128] (pixel-major = MFMA A layout)
    const unsigned short* arow = xc + ((size_t)b * HW + h * 64) * 128;
    bf16x8 afr[4][4];
    #pragma unroll
    for (int mt = 0; mt < 4; ++mt)
        #pragma unroll
        for (int kc = 0; kc < 4; ++kc)
            afr[mt][kc] = *reinterpret_cast<const bf16x8*>(
                &arow[(size_t)(mt * 16 + lr) * 128 + kc * 32 + lg * 8]);

    const float* xrow = x + (size_t)b * 128 * HW + h * 64;
    float* obase = out + (size_t)b * 128 * HW + h * 64;
    #pragma unroll
    for (int nt = 0; nt < 2; ++nt) {
        const int o = wid * 32 + nt * 16 + lr;
        const float bias = b5[o];
        f32x4 acc[4];
        #pragma unroll
        for (int mt = 0; mt < 4; ++mt) acc[mt] = f32x4{bias, bias, bias, bias};
        #pragma unroll
        for (int kc = 0; kc < 4; ++kc) {
            const bf16x8 bfr = *reinterpret_cast<const bf16x8*>(&wb5[(size_t)o * 128 + kc * 32 + lg * 8]);
            #pragma unroll
            for (int mt = 0; mt < 4; ++mt)
                acc[mt] = __builtin_amdgcn_mfma_f32_16x16x32_bf16(afr[mt][kc], bfr, acc[mt], 0, 0, 0);
        }
        #pragma unroll
        for (int mt = 0; mt < 4; ++mt) {
            const size_t off = (size_t)o * HW + mt * 16 + lg * 4;
            const f32x4 xr = *reinterpret_cast<const f32x4*>(&xrow[off]);
            const f32x4 r = acc[mt] + xr;
            *reinterpret_cast<f32x4*>(&obase[off]) = r;
        }
    }
}

extern "C" void kernel_launch(void* const* d_in, const int* in_sizes, int n_in,
                              void* d_out, int out_size, void* d_ws, size_t ws_size,
                              hipStream_t stream) {
    const float* x  = (const float*)d_in[0];
    const float* ng = (const float*)d_in[1];
    const float* nb = (const float*)d_in[2];
    const float* w1 = (const float*)d_in[3];
    const float* b1 = (const float*)d_in[4];
    const float* w2 = (const float*)d_in[5];
    const float* b2 = (const float*)d_in[6];
    const float* qw = (const float*)d_in[7];
    const float* qb = (const float*)d_in[8];
    const float* kw = (const float*)d_in[9];
    const float* kb = (const float*)d_in[10];
    const float* vw = (const float*)d_in[11];
    const float* vb = (const float*)d_in[12];
    const float* w3 = (const float*)d_in[13];
    const float* b3 = (const float*)d_in[14];
    const float* w4 = (const float*)d_in[15];
    const float* b4 = (const float*)d_in[16];
    const float* w5 = (const float*)d_in[17];
    const float* b5 = (const float*)d_in[18];
    float* out = (float*)d_out;

    unsigned short* gqb  = (unsigned short*)d_ws;       // 8388608 bf16 [b][gh][cg][n]
    float* gkp = (float*)(gqb + 8388608);               // 131072 f32   [b][gh][m][cg]
    float* gvp = gkp + 131072;                          // 131072 f32
    unsigned short* lqkv = (unsigned short*)(gvp + 131072);  // 3*APL bf16 row-padded planes
    unsigned short* xc   = lqkv + 3 * APL;              // 16777216 bf16 [b][n][128]
    unsigned short* wcat = xc + 16777216;               // 384*64 bf16
    unsigned short* wb5  = wcat + 384 * 64;             // 128*128 bf16
    float* bcat = (float*)(wb5 + 128 * 128);            // 384 f32 (b2|b1)

    kprep<<<96, 256, 0, stream>>>(w1, w2, w5, b1, b2, wcat, wb5, bcat);
    hipMemsetAsync(gkp, 0, 2 * 131072 * sizeof(float), stream);
    k1_ln_fc<<<2048, 256, 0, stream>>>(x, ng, nb, wcat, bcat, gqb, gkp, gvp, lqkv);
    k2_attn<<<2048, 256, 0, stream>>>(gqb, gkp, gvp, xc);
    k3_local<<<2048, 256, 0, stream>>>(lqkv, qw, qb, kw, kb, vw, vb,
                                       w3, b3, w4, b4, xc);
    k4_fc5<<<2048, 256, 0, stream>>>(x, xc, wb5, b5, out);
}